// Round 12
// baseline (155.441 us; speedup 1.0000x reference)
//
#include <hip/hip_runtime.h>
#include <hip/hip_bf16.h>
#include <cstdint>

// Problem constants
#define NN   4
#define LL   4096      // 64*64
#define DD   18
#define CVV  128
#define CIN  256
#define CUU  10
#define HH   129
#define COO  10

typedef unsigned short ushort_t;
typedef __attribute__((ext_vector_type(8))) short short8v;   // 8 bf16 (4 VGPRs)
typedef __attribute__((ext_vector_type(4))) short short4v;   // 4 bf16
typedef __attribute__((ext_vector_type(4))) float f32x4;

// workspace layout (float offsets)
#define PB_OFF   ((size_t)0)          // p bf16 [4][256][4096] = 2097152 f (dead after qk2f/val_gemm3)
#define OP_OFF   ((size_t)2097152)    // out_pre fp32 [4][10][4096] = 163840 f
#define VAL_OFF  ((size_t)2260992)    // val bf16 [4][128][4096] = 1048576 f (later Lp[2][16384]+ypart[2][16384][10])
#define QT_OFF   ((size_t)3309568)    // qt bf16 [4][4096][32] = 262144 f
#define KT_OFF   ((size_t)3571712)    // kt bf16 tile-swizzled [4][64][4KB] = 262144 f
#define VT_OFF   ((size_t)3833856)    // vt bf16 tile-swizzled [4][64][16KB] = 1048576 f
#define VSC_OFF  ((size_t)4882432)
#define VSH_OFF  ((size_t)4882560)
#define S2_OFF   ((size_t)4882688)
#define SH2_OFF  ((size_t)4882704)
#define PART_OFF ((size_t)4882720)    // val-BN partials [512][8][4][2] = 32768 f
#define PART2_OFF ((size_t)4915488)   // out-BN partials [64][10][2] = 1280 f
#define KMAX_OFF ((size_t)4916768)    // kmax int bits [4][32]
// total ~4916896 f = 19.7 MB

static __device__ __forceinline__ ushort_t f2bf(float x) {
    unsigned int u = __float_as_uint(x);
    unsigned int r = (u + 0x7fffu + ((u >> 16) & 1u)) >> 16;
    return (ushort_t)r;
}
static __device__ __forceinline__ float bf2f(ushort_t b) {
    return __uint_as_float(((unsigned int)b) << 16);
}

static __device__ __forceinline__ void gload16(const void* g, void* l) {
    __builtin_amdgcn_global_load_lds(
        (const __attribute__((address_space(1))) void*)g,
        (__attribute__((address_space(3))) void*)l, 16, 0, 0);
}

// ---------------- avg pool 3x3 stride 2 -> bf16, LDS row staging (+ kmax zeroing) ----------------
__global__ __launch_bounds__(256) void pool_bf_kernel(const float* __restrict__ src,
                                                      ushort_t* __restrict__ dst,
                                                      int* __restrict__ kz) {
    if (kz != nullptr && blockIdx.x == 0 && threadIdx.x < 128) kz[threadIdx.x] = 0;
    int b = blockIdx.x;
    int plane = b >> 4;
    int rg = b & 15;
    __shared__ float rows[9][132];
    const float* sp = src + (size_t)plane * (HH * HH) + (size_t)(rg * 8) * HH;
    #pragma unroll
    for (int j = 0; j < 9; ++j) {
        if (threadIdx.x < HH) rows[j][threadIdx.x] = sp[(size_t)j * HH + threadIdx.x];
    }
    __syncthreads();
    int row = threadIdx.x >> 6, ow = threadIdx.x & 63;
    const float* r0 = rows[2 * row];
    const float* r1 = rows[2 * row + 1];
    const float* r2 = rows[2 * row + 2];
    int x = 2 * ow;
    float sum = r0[x] + r0[x + 1] + r0[x + 2]
              + r1[x] + r1[x + 1] + r1[x + 2]
              + r2[x] + r2[x + 1] + r2[x + 2];
    dst[(size_t)plane * 4096 + (size_t)(rg * 4 + row) * 64 + ow] = f2bf(sum * (1.0f / 9.0f));
}

// ---------------- query + key 1x1 convs (bf16 p), fused u-pool, kt swizzled, kmax atomicMax ----------------
__global__ __launch_bounds__(256) void qk2f_kernel(const ushort_t* __restrict__ pb,
                                                   const float* __restrict__ hu,
                                                   const float* __restrict__ Wq,
                                                   const float* __restrict__ Wk,
                                                   ushort_t* __restrict__ qt,
                                                   char* __restrict__ kt_c,
                                                   int* __restrict__ kmaxb) {
    int n = blockIdx.x >> 6;
    int mb = blockIdx.x & 63;
    int tid = threadIdx.x;
    int mloc = tid & 63;
    int cs = tid >> 6;
    int m = mb * 64 + mloc;
    int hi = m >> 6, wi = m & 63;

    __shared__ float kacc[4][64][21];

    float coord[8];
    coord[0] = wi * (2.0f / 64.0f) - 1.0f;
    coord[1] = hi * (2.0f / 64.0f) - 1.0f;
    coord[2] = (wi + 1) * (2.0f / 64.0f) - 1.0f;
    coord[3] = (hi + 1) * (2.0f / 64.0f) - 1.0f;
    coord[4] = 0.5f * (coord[0] + coord[2]);
    coord[5] = 0.5f * (coord[1] + coord[3]);
    coord[6] = 1.0f / 64.0f;
    coord[7] = 1.0f / 64.0f;

    // K partial over c in [cs*64, cs*64+64)
    {
        float acc[DD];
        #pragma unroll
        for (int o = 0; o < DD; ++o) acc[o] = 0.0f;
        const ushort_t* pc = pb + ((size_t)(n * CIN + cs * 64)) * LL + m;
        for (int c0 = 0; c0 < 64; ++c0) {
            float pv = bf2f(pc[(size_t)c0 * LL]);
            const float* wr = Wk + (cs * 64 + c0);
            #pragma unroll
            for (int o = 0; o < DD; ++o) acc[o] = fmaf(pv, wr[o * 264], acc[o]);
        }
        if (cs == 3) {
            #pragma unroll
            for (int j = 0; j < 8; ++j) {
                float cv = coord[j];
                #pragma unroll
                for (int o = 0; o < DD; ++o) acc[o] = fmaf(cv, Wk[o * 264 + CIN + j], acc[o]);
            }
        }
        #pragma unroll
        for (int o = 0; o < DD; ++o) kacc[cs][mloc][o] = acc[o];
    }
    // Q full on wave 0, with inline 3x3 s2 pooling of hu
    if (cs == 0) {
        float acc[DD];
        #pragma unroll
        for (int o = 0; o < DD; ++o) acc[o] = 0.0f;
        const float* hub = hu + ((size_t)(n * CUU)) * (HH * HH) + (size_t)(2 * hi) * HH + 2 * wi;
        for (int cq = 0; cq < CUU; ++cq) {
            const float* s = hub + (size_t)cq * (HH * HH);
            float uv = (s[0] + s[1] + s[2]
                      + s[HH] + s[HH + 1] + s[HH + 2]
                      + s[2 * HH] + s[2 * HH + 1] + s[2 * HH + 2]) * (1.0f / 9.0f);
            #pragma unroll
            for (int o = 0; o < DD; ++o) acc[o] = fmaf(uv, Wq[o * DD + cq], acc[o]);
        }
        #pragma unroll
        for (int j = 0; j < 8; ++j) {
            float cv = coord[j];
            #pragma unroll
            for (int o = 0; o < DD; ++o) acc[o] = fmaf(cv, Wq[o * DD + CUU + j], acc[o]);
        }
        union { short8v v[4]; ushort_t s[32]; } pk;
        #pragma unroll
        for (int o = 0; o < 32; ++o) pk.s[o] = (o < DD) ? f2bf(acc[o]) : (ushort_t)0;
        short8v* qrow = (short8v*)(qt + ((size_t)(n * LL) + m) * 32);
        #pragma unroll
        for (int j = 0; j < 4; ++j) qrow[j] = pk.v[j];
    }
    __syncthreads();
    // reduce 4 partials, write kt tile-swizzled; collect per-o max|k|
    {
        int j = cs;
        union { short8v v; ushort_t s[8]; } pk;
        #pragma unroll
        for (int i = 0; i < 8; ++i) {
            int o = j * 8 + i;
            float v = 0.0f;
            if (o < DD)
                v = kacc[0][mloc][o] + kacc[1][mloc][o] + kacc[2][mloc][o] + kacc[3][mloc][o];
            pk.s[i] = (o < DD) ? f2bf(v) : (ushort_t)0;
        }
        int byte = ((mloc << 6) | (j << 4)) ^ (((mloc >> 1) & 7) << 4);
        *(short8v*)(kt_c + (size_t)n * 262144 + (size_t)mb * 4096 + byte) = pk.v;

        int mb8[8];
        #pragma unroll
        for (int i = 0; i < 8; ++i) mb8[i] = (int)(pk.s[i] & 0x7fffu);
        #pragma unroll
        for (int off = 1; off < 64; off <<= 1) {
            #pragma unroll
            for (int i = 0; i < 8; ++i) {
                int ov = __shfl_xor(mb8[i], off);
                mb8[i] = max(mb8[i], ov);
            }
        }
        if (mloc == 0) {
            #pragma unroll
            for (int i = 0; i < 8; ++i)
                atomicMax(&kmaxb[n * 32 + cs * 8 + i], mb8[i] << 16);
        }
    }
}

// ---------------- val GEMM (bf16 in/out) + fused BN1 stat partials ----------------
__global__ __launch_bounds__(256, 2) void val_gemm3_kernel(const ushort_t* __restrict__ pb,
                                                           const float* __restrict__ Wv,
                                                           ushort_t* __restrict__ val,
                                                           float* __restrict__ part) {
    int b = blockIdx.x;          // 512 blocks: n(4) x cb(4) x mb(32)
    int n  = b >> 7;
    int cb = (b >> 5) & 3;
    int mb = b & 31;
    int tid = threadIdx.x;
    int cg = tid >> 5;           // 8 groups x 4ch
    int mg = tid & 31;           // 32 groups x 4m
    int ch0 = cb * 32;
    int m0 = mb * 128;

    __shared__ float Wt[256][36];

    {
        int c4 = tid & 63;
        int chq = tid >> 6;
        #pragma unroll
        for (int j = 0; j < 8; ++j) {
            int ch = chq * 8 + j;
            float4 v = *(const float4*)&Wv[(size_t)(ch0 + ch) * CIN + c4 * 4];
            Wt[c4 * 4 + 0][ch] = v.x;
            Wt[c4 * 4 + 1][ch] = v.y;
            Wt[c4 * 4 + 2][ch] = v.z;
            Wt[c4 * 4 + 3][ch] = v.w;
        }
    }
    __syncthreads();

    const ushort_t* pbb = pb + (size_t)n * CIN * LL + m0 + mg * 4;
    f32x4 a0 = {0.f,0.f,0.f,0.f}, a1 = {0.f,0.f,0.f,0.f};
    f32x4 a2 = {0.f,0.f,0.f,0.f}, a3 = {0.f,0.f,0.f,0.f};

    #pragma unroll 4
    for (int c = 0; c < CIN; ++c) {
        short4v ps = *(const short4v*)(pbb + (size_t)c * LL);
        f32x4 pv;
        pv[0] = bf2f((ushort_t)ps[0]); pv[1] = bf2f((ushort_t)ps[1]);
        pv[2] = bf2f((ushort_t)ps[2]); pv[3] = bf2f((ushort_t)ps[3]);
        f32x4 wv = *(const f32x4*)&Wt[c][cg * 4];
        a0 += pv * wv.x;
        a1 += pv * wv.y;
        a2 += pv * wv.z;
        a3 += pv * wv.w;
    }

    // write bf16 val
    size_t out = ((size_t)(n * CVV + ch0 + cg * 4)) * LL + m0 + mg * 4;
    union { short4v v; ushort_t s[4]; } w0, w1, w2, w3;
    #pragma unroll
    for (int i = 0; i < 4; ++i) {
        w0.s[i] = f2bf(a0[i]); w1.s[i] = f2bf(a1[i]);
        w2.s[i] = f2bf(a2[i]); w3.s[i] = f2bf(a3[i]);
    }
    *(short4v*)&val[out]          = w0.v;
    *(short4v*)&val[out + LL]     = w1.v;
    *(short4v*)&val[out + 2*LL]   = w2.v;
    *(short4v*)&val[out + 3*LL]   = w3.v;

    // fused BN stat partials: per-thread sums over 4 m, reduce across the 32 mg lanes
    float s1[4], s2[4];
    s1[0] = a0[0]+a0[1]+a0[2]+a0[3]; s2[0] = a0[0]*a0[0]+a0[1]*a0[1]+a0[2]*a0[2]+a0[3]*a0[3];
    s1[1] = a1[0]+a1[1]+a1[2]+a1[3]; s2[1] = a1[0]*a1[0]+a1[1]*a1[1]+a1[2]*a1[2]+a1[3]*a1[3];
    s1[2] = a2[0]+a2[1]+a2[2]+a2[3]; s2[2] = a2[0]*a2[0]+a2[1]*a2[1]+a2[2]*a2[2]+a2[3]*a2[3];
    s1[3] = a3[0]+a3[1]+a3[2]+a3[3]; s2[3] = a3[0]*a3[0]+a3[1]*a3[1]+a3[2]*a3[2]+a3[3]*a3[3];
    #pragma unroll
    for (int off = 1; off < 32; off <<= 1) {
        #pragma unroll
        for (int i = 0; i < 4; ++i) {
            s1[i] += __shfl_xor(s1[i], off);
            s2[i] += __shfl_xor(s2[i], off);
        }
    }
    if (mg == 0) {
        #pragma unroll
        for (int i = 0; i < 4; ++i) {
            part[(((size_t)b * 8 + cg) * 4 + i) * 2]     = s1[i];
            part[(((size_t)b * 8 + cg) * 4 + i) * 2 + 1] = s2[i];
        }
    }
}

// ---------------- BN1 finalize from val_gemm partials ----------------
__global__ __launch_bounds__(128) void bn_finalize_v_kernel(const float* __restrict__ part,
                                                            const float* __restrict__ g,
                                                            const float* __restrict__ bta,
                                                            float* __restrict__ scale,
                                                            float* __restrict__ shift) {
    int ch = threadIdx.x;
    if (ch >= CVV) return;
    int cb = ch >> 5;
    int cg = (ch & 31) >> 2;
    int i = ch & 3;
    float s1 = 0.0f, s2 = 0.0f;
    for (int n = 0; n < NN; ++n) {
        for (int mb = 0; mb < 32; ++mb) {
            int b = n * 128 + cb * 32 + mb;
            size_t idx = (((size_t)b * 8 + cg) * 4 + i) * 2;
            s1 += part[idx];
            s2 += part[idx + 1];
        }
    }
    float mean = s1 * (1.0f / (NN * LL));
    float var = s2 * (1.0f / (NN * LL)) - mean * mean;
    float inv = rsqrtf(var + 1e-5f);
    float sc = g[ch] * inv;
    scale[ch] = sc;
    shift[ch] = bta[ch] - mean * sc;
}

// ---------------- apply BN + relu on bf16 val -> swizzled bf16 vt, 8 m/thread ----------------
__global__ __launch_bounds__(256) void bn_apply2_kernel(const ushort_t* __restrict__ val,
                                                        const float* __restrict__ scale,
                                                        const float* __restrict__ shift,
                                                        char* __restrict__ vt_c) {
    int t = blockIdx.x * 256 + threadIdx.x;   // over NN*CVV*512
    int mq = t & 511;
    int ch = (t >> 9) & 127;
    int n = t >> 16;
    int m0 = mq * 8;
    short8v vs = *(const short8v*)(val + ((size_t)(n * CVV + ch)) * LL + m0);
    float sc = scale[ch], sh = shift[ch];
    union { short8v v; ushort_t s[8]; } pk;
    #pragma unroll
    for (int i = 0; i < 8; ++i)
        pk.s[i] = f2bf(fmaxf(fmaf(bf2f((ushort_t)vs[i]), sc, sh), 0.0f));
    int tile = m0 >> 6, mloc = m0 & 63;
    size_t byte = (size_t)n * 1048576 + (size_t)tile * 16384
                + (size_t)(((ch << 7) | (mloc << 1)) ^ ((ch & 7) << 4));
    *(short8v*)(vt_c + byte) = pk.v;
}

// ---------------- flash attention + fused projection: LDS-staged K/V, 2-way m-split ----------------
struct PW { ushort_t p[16][72]; };

__global__ __launch_bounds__(256, 2) void attn_proj_kernel(const ushort_t* __restrict__ qt,
                                                           const char* __restrict__ kt_c,
                                                           const char* __restrict__ vt_c,
                                                           const int* __restrict__ kmaxb,
                                                           const float* __restrict__ Wp,
                                                           float* __restrict__ ypart,
                                                           float* __restrict__ Lp) {
    int orig = blockIdx.x;                       // 512
    int bid = ((orig & 7) << 6) | (orig >> 3);   // XCD-pinned: (n,sM) per XCD
    int qb = bid & 63;
    int sM = (bid >> 6) & 1;
    int n = bid >> 7;
    int tid = threadIdx.x;
    int w = tid >> 6, lane = tid & 63, c = lane & 15, g = lane >> 4;
    int l0w = qb * 64 + w * 16;

    __shared__ __align__(16) ushort_t K_t[2][2048];   // 2 x 4KB
    __shared__ __align__(16) ushort_t V_t[2][8192];   // 2 x 16KB
    __shared__ PW pws[4];
    __shared__ float Wpl[COO][CVV];                   // 5KB staged Wp

    for (int i = tid; i < COO * CVV; i += 256) Wpl[i >> 7][i & 127] = Wp[i];

    const char* ktb = kt_c + (size_t)n * 262144;
    const char* vtb = vt_c + (size_t)n * 1048576;
    int tk64 = sM * 32;

    short8v qf = *(const short8v*)(qt + (((size_t)n * LL + l0w + c) << 5) + g * 8);
    int vxor = (c & 7) << 4;

    // ---- analytic row-max bound ----
    float bound = 0.0f;
    {
        const int* km = kmaxb + n * 32 + g * 8;
        #pragma unroll
        for (int i = 0; i < 8; ++i) {
            float kv = __int_as_float(km[i]);
            float aq = __uint_as_float(((unsigned int)((ushort_t)qf[i]) & 0x7fffu) << 16);
            bound = fmaf(aq, kv, bound);
        }
        bound += __shfl_xor(bound, 16);
        bound += __shfl_xor(bound, 32);
    }
    float M[4];
    #pragma unroll
    for (int r = 0; r < 4; ++r) M[r] = __shfl(bound, g * 4 + r);

    f32x4 O[8];
    #pragma unroll
    for (int i = 0; i < 8; ++i) O[i] = (f32x4){0.f, 0.f, 0.f, 0.f};
    float Lacc[4] = {0.f, 0.f, 0.f, 0.f};

    {
        const char* ks = ktb + (size_t)tk64 * 4096 + w * 1024 + lane * 16;
        gload16(ks, (char*)K_t[0] + w * 1024);
        const char* vs = vtb + (size_t)tk64 * 16384 + w * 4096 + lane * 16;
        #pragma unroll
        for (int i = 0; i < 4; ++i)
            gload16(vs + i * 1024, (char*)V_t[0] + w * 4096 + i * 1024);
    }
    __syncthreads();
    int buf = 0;
    for (int mt = 0; mt < 32; ++mt) {
        if (mt + 1 < 32) {
            const char* ks = ktb + (size_t)(tk64 + mt + 1) * 4096 + w * 1024 + lane * 16;
            gload16(ks, (char*)K_t[buf ^ 1] + w * 1024);
            const char* vs = vtb + (size_t)(tk64 + mt + 1) * 16384 + w * 4096 + lane * 16;
            #pragma unroll
            for (int i = 0; i < 4; ++i)
                gload16(vs + i * 1024, (char*)V_t[buf ^ 1] + w * 4096 + i * 1024);
        }
        // QK
        f32x4 S[4];
        const char* kb = (const char*)K_t[buf];
        #pragma unroll
        for (int t = 0; t < 4; ++t) {
            int krow = t * 16 + c;
            int kby = ((krow << 6) | (g << 4)) ^ (((krow >> 1) & 7) << 4);
            short8v kf = *(const short8v*)(kb + kby);
            S[t] = __builtin_amdgcn_mfma_f32_16x16x32_bf16(qf, kf, (f32x4){0.f, 0.f, 0.f, 0.f}, 0, 0, 0);
        }
        // exp + P tile (wave-private)
        #pragma unroll
        for (int t = 0; t < 4; ++t) {
            #pragma unroll
            for (int r = 0; r < 4; ++r) {
                float pv = __expf(S[t][r] - M[r]);
                Lacc[r] += pv;
                pws[w].p[g * 4 + r][t * 16 + c] = f2bf(pv);
            }
        }
        short8v pa0 = *(const short8v*)&pws[w].p[c][g * 8];
        short8v pa1 = *(const short8v*)&pws[w].p[c][32 + g * 8];
        // PV
        const char* vb = (const char*)V_t[buf];
        __builtin_amdgcn_s_setprio(1);
        #pragma unroll
        for (int ct = 0; ct < 8; ++ct) {
            int row = ct * 16 + c;
            int vby0 = (row << 7) | ((g << 4) ^ vxor);
            int vby1 = (row << 7) | (((1 << 6) | (g << 4)) ^ vxor);
            short8v v0 = *(const short8v*)(vb + vby0);
            short8v v1 = *(const short8v*)(vb + vby1);
            O[ct] = __builtin_amdgcn_mfma_f32_16x16x32_bf16(pa0, v0, O[ct], 0, 0, 0);
            O[ct] = __builtin_amdgcn_mfma_f32_16x16x32_bf16(pa1, v1, O[ct], 0, 0, 0);
        }
        __builtin_amdgcn_s_setprio(0);
        __syncthreads();
        buf ^= 1;
    }
    #pragma unroll
    for (int off = 1; off < 16; off <<= 1) {
        #pragma unroll
        for (int r = 0; r < 4; ++r) Lacc[r] += __shfl_xor(Lacc[r], off);
    }

    // ---- fused projection ----
    float yp[COO][4];
    #pragma unroll
    for (int o = 0; o < COO; ++o)
        #pragma unroll
        for (int r = 0; r < 4; ++r) yp[o][r] = 0.0f;
    #pragma unroll
    for (int ct = 0; ct < 8; ++ct) {
        #pragma unroll
        for (int o = 0; o < COO; ++o) {
            float wv = Wpl[o][ct * 16 + c];
            #pragma unroll
            for (int r = 0; r < 4; ++r)
                yp[o][r] = fmaf(O[ct][r], wv, yp[o][r]);
        }
    }
    #pragma unroll
    for (int off = 1; off < 16; off <<= 1) {
        #pragma unroll
        for (int o = 0; o < COO; ++o)
            #pragma unroll
            for (int r = 0; r < 4; ++r)
                yp[o][r] += __shfl_xor(yp[o][r], off);
    }
    if (c == 0) {
        #pragma unroll
        for (int r = 0; r < 4; ++r) {
            size_t yrow = (size_t)(sM * (NN * LL) + n * LL + l0w + g * 4 + r);
            #pragma unroll
            for (int o = 0; o < COO; ++o)
                ypart[yrow * COO + o] = yp[o][r];
            Lp[yrow] = Lacc[r];
        }
    }
}

// ---------------- combine 2 m-splits + fused BN2 stat partials ----------------
__global__ __launch_bounds__(256) void combine2b_kernel(const float* __restrict__ ypart,
                                                        const float* __restrict__ Lp,
                                                        float* __restrict__ out_pre,
                                                        float* __restrict__ part2) {
    int idx = blockIdx.x * 256 + threadIdx.x;   // over NN*LL (64 blocks)
    int n = idx >> 12;
    int l = idx & 4095;
    int nl = n * LL + l;
    float inv = 1.0f / (Lp[nl] + Lp[NN * LL + nl]);
    const float* y0 = ypart + (size_t)nl * COO;
    const float* y1 = ypart + ((size_t)(NN * LL) + nl) * COO;
    float ov[COO];
    #pragma unroll
    for (int o = 0; o < COO; ++o) {
        ov[o] = (y0[o] + y1[o]) * inv;
        out_pre[((size_t)(n * COO + o)) * LL + l] = ov[o];
    }
    // BN2 partials
    float p1[COO], p2[COO];
    #pragma unroll
    for (int o = 0; o < COO; ++o) { p1[o] = ov[o]; p2[o] = ov[o] * ov[o]; }
    #pragma unroll
    for (int off = 1; off < 64; off <<= 1) {
        #pragma unroll
        for (int o = 0; o < COO; ++o) {
            p1[o] += __shfl_xor(p1[o], off);
            p2[o] += __shfl_xor(p2[o], off);
        }
    }
    __shared__ float rs1[4][COO], rs2[4][COO];
    int w = threadIdx.x >> 6, lane = threadIdx.x & 63;
    if (lane == 0) {
        #pragma unroll
        for (int o = 0; o < COO; ++o) { rs1[w][o] = p1[o]; rs2[w][o] = p2[o]; }
    }
    __syncthreads();
    if (threadIdx.x < COO) {
        int o = threadIdx.x;
        float a = rs1[0][o] + rs1[1][o] + rs1[2][o] + rs1[3][o];
        float b = rs2[0][o] + rs2[1][o] + rs2[2][o] + rs2[3][o];
        part2[((size_t)blockIdx.x * COO + o) * 2]     = a;
        part2[((size_t)blockIdx.x * COO + o) * 2 + 1] = b;
    }
}

// ---------------- BN2 finalize ----------------
__global__ __launch_bounds__(64) void bn_finalize2_kernel(const float* __restrict__ part2,
                                                          const float* __restrict__ g,
                                                          const float* __restrict__ bta,
                                                          float* __restrict__ scale,
                                                          float* __restrict__ shift) {
    int ch = threadIdx.x;
    if (ch >= COO) return;
    float s1 = 0.0f, s2 = 0.0f;
    for (int b = 0; b < 64; ++b) {
        s1 += part2[((size_t)b * COO + ch) * 2];
        s2 += part2[((size_t)b * COO + ch) * 2 + 1];
    }
    float mean = s1 * (1.0f / (NN * LL));
    float var = s2 * (1.0f / (NN * LL)) - mean * mean;
    float inv = rsqrtf(var + 1e-5f);
    float sc = g[ch] * inv;
    scale[ch] = sc;
    shift[ch] = bta[ch] - mean * sc;
}

// ---------------- BN + relu + bilinear resize (align_corners=True) ----------------
__global__ __launch_bounds__(256) void resize_kernel(const float* __restrict__ out_pre,
                                                     const float* __restrict__ scale,
                                                     const float* __restrict__ shift,
                                                     float* __restrict__ out,
                                                     int total) {
    int idx = blockIdx.x * 256 + threadIdx.x;
    if (idx >= total) return;
    int ow = idx % HH;
    int t = idx / HH;
    int oh = t % HH;
    int t2 = t / HH;
    int o = t2 % COO;
    int n = t2 / COO;

    const float r = 63.0f / 128.0f;
    float y = oh * r;
    float x = ow * r;
    int y0 = (int)y;
    int x0 = (int)x;
    float wy = y - y0;
    float wx = x - x0;
    int y1 = min(y0 + 1, 63);
    int x1 = min(x0 + 1, 63);

    const float* base = out_pre + ((size_t)(n * COO + o)) * LL;
    float sc = scale[o], sh = shift[o];
    float v00 = fmaxf(fmaf(base[y0 * 64 + x0], sc, sh), 0.0f);
    float v01 = fmaxf(fmaf(base[y0 * 64 + x1], sc, sh), 0.0f);
    float v10 = fmaxf(fmaf(base[y1 * 64 + x0], sc, sh), 0.0f);
    float v11 = fmaxf(fmaf(base[y1 * 64 + x1], sc, sh), 0.0f);
    float top = v00 * (1.0f - wx) + v01 * wx;
    float bot = v10 * (1.0f - wx) + v11 * wx;
    out[idx] = top * (1.0f - wy) + bot * wy;
}

extern "C" void kernel_launch(void* const* d_in, const int* in_sizes, int n_in,
                              void* d_out, int out_size, void* d_ws, size_t ws_size,
                              hipStream_t stream) {
    (void)in_sizes; (void)n_in; (void)out_size; (void)ws_size;
    const float* p_fea = (const float*)d_in[0];
    const float* hu    = (const float*)d_in[1];
    const float* Wq    = (const float*)d_in[2];
    const float* Wk    = (const float*)d_in[3];
    const float* Wv    = (const float*)d_in[4];
    const float* g_v   = (const float*)d_in[5];
    const float* b_v   = (const float*)d_in[6];
    const float* Wp    = (const float*)d_in[7];
    const float* g_p   = (const float*)d_in[8];
    const float* b_p   = (const float*)d_in[9];

    float* ws = (float*)d_ws;
    ushort_t* pbb     = (ushort_t*)(ws + PB_OFF);
    float*    out_pre = ws + OP_OFF;
    ushort_t* valb    = (ushort_t*)(ws + VAL_OFF);
    ushort_t* qtb     = (ushort_t*)(ws + QT_OFF);
    char*     ktb     = (char*)(ws + KT_OFF);
    char*     vtb     = (char*)(ws + VT_OFF);
    float*    Lpart   = ws + VAL_OFF;             // alias: val dead after bn_apply2
    float*    ypart   = ws + VAL_OFF + 32768;     // [2][16384][10]
    float*    vscale  = ws + VSC_OFF;
    float*    vshift  = ws + VSH_OFF;
    float*    scale2  = ws + S2_OFF;
    float*    shift2  = ws + SH2_OFF;
    float*    part    = ws + PART_OFF;
    float*    part2   = ws + PART2_OFF;
    int*      kmaxb   = (int*)(ws + KMAX_OFF);

    pool_bf_kernel<<<NN * CIN * 16, 256, 0, stream>>>(p_fea, pbb, kmaxb);
    qk2f_kernel<<<256, 256, 0, stream>>>(pbb, hu, Wq, Wk, qtb, ktb, kmaxb);
    val_gemm3_kernel<<<512, 256, 0, stream>>>(pbb, Wv, valb, part);
    bn_finalize_v_kernel<<<1, 128, 0, stream>>>(part, g_v, b_v, vscale, vshift);
    bn_apply2_kernel<<<(NN * CVV * 512) / 256, 256, 0, stream>>>(valb, vscale, vshift, vtb);
    attn_proj_kernel<<<512, 256, 0, stream>>>(qtb, ktb, vtb, kmaxb, Wp, ypart, Lpart);
    combine2b_kernel<<<(NN * LL) / 256, 256, 0, stream>>>(ypart, Lpart, out_pre, part2);
    bn_finalize2_kernel<<<1, 64, 0, stream>>>(part2, g_p, b_p, scale2, shift2);
    {
        int total = NN * COO * HH * HH;
        resize_kernel<<<(total + 255) / 256, 256, 0, stream>>>(out_pre, scale2, shift2,
                                                               (float*)d_out, total);
    }
}

// Round 14
// 140.546 us; speedup vs baseline: 1.1060x; 1.1060x over previous
//
#include <hip/hip_runtime.h>
#include <hip/hip_bf16.h>
#include <cstdint>

// Problem constants
#define NN   4
#define LL   4096      // 64*64
#define DD   18
#define CVV  128
#define CIN  256
#define CUU  10
#define HH   129
#define COO  10

typedef unsigned short ushort_t;
typedef __attribute__((ext_vector_type(8))) short short8v;   // 8 bf16 (4 VGPRs)
typedef __attribute__((ext_vector_type(4))) short short4v;   // 4 bf16
typedef __attribute__((ext_vector_type(4))) float f32x4;

// workspace layout (float offsets)
#define PB_OFF   ((size_t)0)          // p bf16 [4][256][4096] = 2097152 f
#define OP_OFF   ((size_t)2097152)    // out_pre fp32 [4][10][4096] = 163840 f
#define VAL_OFF  ((size_t)2260992)    // val bf16 = 1048576 f (later Lp[4][16384]+ypart[4][16384][10])
#define QT_OFF   ((size_t)3309568)    // qt bf16 [4][4096][32] = 262144 f
#define KT_OFF   ((size_t)3571712)    // kt bf16 tile-swizzled [4][64][4KB] = 262144 f
#define VT_OFF   ((size_t)3833856)    // vt bf16 tile-swizzled [4][128][8KB] = 1048576 f
#define VSC_OFF  ((size_t)4882432)
#define VSH_OFF  ((size_t)4882560)
#define S2_OFF   ((size_t)4882688)
#define SH2_OFF  ((size_t)4882704)
#define PART_OFF ((size_t)4882720)    // val-BN partials [512][8][4][2] = 32768 f
#define PART2_OFF ((size_t)4915488)   // out-BN partials [64][10][2] = 1280 f
#define KMAX_OFF ((size_t)4916768)    // kmax int bits [4][32]
// total ~4916896 f = 19.7 MB

static __device__ __forceinline__ ushort_t f2bf(float x) {
    unsigned int u = __float_as_uint(x);
    unsigned int r = (u + 0x7fffu + ((u >> 16) & 1u)) >> 16;
    return (ushort_t)r;
}
static __device__ __forceinline__ float bf2f(ushort_t b) {
    return __uint_as_float(((unsigned int)b) << 16);
}
static __device__ __forceinline__ unsigned int pk2(float a, float b) {
    return (unsigned int)f2bf(a) | ((unsigned int)f2bf(b) << 16);
}

static __device__ __forceinline__ void gload16(const void* g, void* l) {
    __builtin_amdgcn_global_load_lds(
        (const __attribute__((address_space(1))) void*)g,
        (__attribute__((address_space(3))) void*)l, 16, 0, 0);
}

// ---------------- avg pool 3x3 stride 2 -> bf16 (+ kmax zeroing) ----------------
__global__ __launch_bounds__(256) void pool_bf_kernel(const float* __restrict__ src,
                                                      ushort_t* __restrict__ dst,
                                                      int* __restrict__ kz) {
    if (kz != nullptr && blockIdx.x == 0 && threadIdx.x < 128) kz[threadIdx.x] = 0;
    int b = blockIdx.x;
    int plane = b >> 4;
    int rg = b & 15;
    __shared__ float rows[9][132];
    const float* sp = src + (size_t)plane * (HH * HH) + (size_t)(rg * 8) * HH;
    #pragma unroll
    for (int j = 0; j < 9; ++j) {
        if (threadIdx.x < HH) rows[j][threadIdx.x] = sp[(size_t)j * HH + threadIdx.x];
    }
    __syncthreads();
    int row = threadIdx.x >> 6, ow = threadIdx.x & 63;
    const float* r0 = rows[2 * row];
    const float* r1 = rows[2 * row + 1];
    const float* r2 = rows[2 * row + 2];
    int x = 2 * ow;
    float sum = r0[x] + r0[x + 1] + r0[x + 2]
              + r1[x] + r1[x + 1] + r1[x + 2]
              + r2[x] + r2[x + 1] + r2[x + 2];
    dst[(size_t)plane * 4096 + (size_t)(rg * 4 + row) * 64 + ow] = f2bf(sum * (1.0f / 9.0f));
}

// ---------------- fat kernel: qk role (blocks 0..255) + val role (blocks 256..767) ----------------
__global__ __launch_bounds__(256, 2) void qkval_kernel(const ushort_t* __restrict__ pb,
                                                       const float* __restrict__ hu,
                                                       const float* __restrict__ Wq,
                                                       const float* __restrict__ Wk,
                                                       const float* __restrict__ Wv,
                                                       ushort_t* __restrict__ qt,
                                                       char* __restrict__ kt_c,
                                                       int* __restrict__ kmaxb,
                                                       ushort_t* __restrict__ val,
                                                       float* __restrict__ part) {
    __shared__ __align__(16) char smem[36864];
    int tid = threadIdx.x;

    if (blockIdx.x < 256) {
        // ===================== QK role =====================
        float (*kacc)[64][21] = (float(*)[64][21])smem;
        int n = blockIdx.x >> 6;
        int mb = blockIdx.x & 63;
        int mloc = tid & 63;
        int cs = tid >> 6;
        int m = mb * 64 + mloc;
        int hi = m >> 6, wi = m & 63;

        float coord[8];
        coord[0] = wi * (2.0f / 64.0f) - 1.0f;
        coord[1] = hi * (2.0f / 64.0f) - 1.0f;
        coord[2] = (wi + 1) * (2.0f / 64.0f) - 1.0f;
        coord[3] = (hi + 1) * (2.0f / 64.0f) - 1.0f;
        coord[4] = 0.5f * (coord[0] + coord[2]);
        coord[5] = 0.5f * (coord[1] + coord[3]);
        coord[6] = 1.0f / 64.0f;
        coord[7] = 1.0f / 64.0f;

        {
            float acc[DD];
            #pragma unroll
            for (int o = 0; o < DD; ++o) acc[o] = 0.0f;
            const ushort_t* pc = pb + ((size_t)(n * CIN + cs * 64)) * LL + m;
            for (int c0 = 0; c0 < 64; ++c0) {
                float pv = bf2f(pc[(size_t)c0 * LL]);
                const float* wr = Wk + (cs * 64 + c0);
                #pragma unroll
                for (int o = 0; o < DD; ++o) acc[o] = fmaf(pv, wr[o * 264], acc[o]);
            }
            if (cs == 3) {
                #pragma unroll
                for (int j = 0; j < 8; ++j) {
                    float cv = coord[j];
                    #pragma unroll
                    for (int o = 0; o < DD; ++o) acc[o] = fmaf(cv, Wk[o * 264 + CIN + j], acc[o]);
                }
            }
            #pragma unroll
            for (int o = 0; o < DD; ++o) kacc[cs][mloc][o] = acc[o];
        }
        if (cs == 0) {
            float acc[DD];
            #pragma unroll
            for (int o = 0; o < DD; ++o) acc[o] = 0.0f;
            const float* hub = hu + ((size_t)(n * CUU)) * (HH * HH) + (size_t)(2 * hi) * HH + 2 * wi;
            for (int cq = 0; cq < CUU; ++cq) {
                const float* s = hub + (size_t)cq * (HH * HH);
                float uv = (s[0] + s[1] + s[2]
                          + s[HH] + s[HH + 1] + s[HH + 2]
                          + s[2 * HH] + s[2 * HH + 1] + s[2 * HH + 2]) * (1.0f / 9.0f);
                #pragma unroll
                for (int o = 0; o < DD; ++o) acc[o] = fmaf(uv, Wq[o * DD + cq], acc[o]);
            }
            #pragma unroll
            for (int j = 0; j < 8; ++j) {
                float cv = coord[j];
                #pragma unroll
                for (int o = 0; o < DD; ++o) acc[o] = fmaf(cv, Wq[o * DD + CUU + j], acc[o]);
            }
            union { short8v v[4]; ushort_t s[32]; } pk;
            #pragma unroll
            for (int o = 0; o < 32; ++o) pk.s[o] = (o < DD) ? f2bf(acc[o]) : (ushort_t)0;
            short8v* qrow = (short8v*)(qt + ((size_t)(n * LL) + m) * 32);
            #pragma unroll
            for (int j = 0; j < 4; ++j) qrow[j] = pk.v[j];
        }
        __syncthreads();
        {
            int j = cs;
            union { short8v v; ushort_t s[8]; } pk;
            #pragma unroll
            for (int i = 0; i < 8; ++i) {
                int o = j * 8 + i;
                float v = 0.0f;
                if (o < DD)
                    v = kacc[0][mloc][o] + kacc[1][mloc][o] + kacc[2][mloc][o] + kacc[3][mloc][o];
                pk.s[i] = (o < DD) ? f2bf(v) : (ushort_t)0;
            }
            int byte = ((mloc << 6) | (j << 4)) ^ (((mloc >> 1) & 7) << 4);
            *(short8v*)(kt_c + (size_t)n * 262144 + (size_t)mb * 4096 + byte) = pk.v;

            int mb8[8];
            #pragma unroll
            for (int i = 0; i < 8; ++i) mb8[i] = (int)(pk.s[i] & 0x7fffu);
            #pragma unroll
            for (int off = 1; off < 64; off <<= 1) {
                #pragma unroll
                for (int i = 0; i < 8; ++i) {
                    int ov = __shfl_xor(mb8[i], off);
                    mb8[i] = max(mb8[i], ov);
                }
            }
            if (mloc == 0) {
                #pragma unroll
                for (int i = 0; i < 8; ++i)
                    atomicMax(&kmaxb[n * 32 + cs * 8 + i], mb8[i] << 16);
            }
        }
    } else {
        // ===================== VAL role =====================
        float (*Wt)[36] = (float(*)[36])smem;
        int b = blockIdx.x - 256;    // 0..511: n(4) x cb(4) x mb(32)
        int n  = b >> 7;
        int cb = (b >> 5) & 3;
        int mb = b & 31;
        int cg = tid >> 5;
        int mg = tid & 31;
        int ch0 = cb * 32;
        int m0 = mb * 128;

        {
            int c4 = tid & 63;
            int chq = tid >> 6;
            #pragma unroll
            for (int j = 0; j < 8; ++j) {
                int ch = chq * 8 + j;
                float4 v = *(const float4*)&Wv[(size_t)(ch0 + ch) * CIN + c4 * 4];
                Wt[c4 * 4 + 0][ch] = v.x;
                Wt[c4 * 4 + 1][ch] = v.y;
                Wt[c4 * 4 + 2][ch] = v.z;
                Wt[c4 * 4 + 3][ch] = v.w;
            }
        }
        __syncthreads();

        const ushort_t* pbb = pb + (size_t)n * CIN * LL + m0 + mg * 4;
        f32x4 a0 = {0.f,0.f,0.f,0.f}, a1 = {0.f,0.f,0.f,0.f};
        f32x4 a2 = {0.f,0.f,0.f,0.f}, a3 = {0.f,0.f,0.f,0.f};

        #pragma unroll 4
        for (int c = 0; c < CIN; ++c) {
            short4v ps = *(const short4v*)(pbb + (size_t)c * LL);
            f32x4 pv;
            pv[0] = bf2f((ushort_t)ps[0]); pv[1] = bf2f((ushort_t)ps[1]);
            pv[2] = bf2f((ushort_t)ps[2]); pv[3] = bf2f((ushort_t)ps[3]);
            f32x4 wv = *(const f32x4*)&Wt[c][cg * 4];
            a0 += pv * wv.x;
            a1 += pv * wv.y;
            a2 += pv * wv.z;
            a3 += pv * wv.w;
        }

        size_t out = ((size_t)(n * CVV + ch0 + cg * 4)) * LL + m0 + mg * 4;
        union { short4v v; ushort_t s[4]; } w0, w1, w2, w3;
        #pragma unroll
        for (int i = 0; i < 4; ++i) {
            w0.s[i] = f2bf(a0[i]); w1.s[i] = f2bf(a1[i]);
            w2.s[i] = f2bf(a2[i]); w3.s[i] = f2bf(a3[i]);
        }
        *(short4v*)&val[out]          = w0.v;
        *(short4v*)&val[out + LL]     = w1.v;
        *(short4v*)&val[out + 2*LL]   = w2.v;
        *(short4v*)&val[out + 3*LL]   = w3.v;

        float s1[4], s2[4];
        s1[0] = a0[0]+a0[1]+a0[2]+a0[3]; s2[0] = a0[0]*a0[0]+a0[1]*a0[1]+a0[2]*a0[2]+a0[3]*a0[3];
        s1[1] = a1[0]+a1[1]+a1[2]+a1[3]; s2[1] = a1[0]*a1[0]+a1[1]*a1[1]+a1[2]*a1[2]+a1[3]*a1[3];
        s1[2] = a2[0]+a2[1]+a2[2]+a2[3]; s2[2] = a2[0]*a2[0]+a2[1]*a2[1]+a2[2]*a2[2]+a2[3]*a2[3];
        s1[3] = a3[0]+a3[1]+a3[2]+a3[3]; s2[3] = a3[0]*a3[0]+a3[1]*a3[1]+a3[2]*a3[2]+a3[3]*a3[3];
        #pragma unroll
        for (int off = 1; off < 32; off <<= 1) {
            #pragma unroll
            for (int i = 0; i < 4; ++i) {
                s1[i] += __shfl_xor(s1[i], off);
                s2[i] += __shfl_xor(s2[i], off);
            }
        }
        if (mg == 0) {
            #pragma unroll
            for (int i = 0; i < 4; ++i) {
                part[(((size_t)b * 8 + cg) * 4 + i) * 2]     = s1[i];
                part[(((size_t)b * 8 + cg) * 4 + i) * 2 + 1] = s2[i];
            }
        }
    }
}

// ---------------- BN1 finalize ----------------
__global__ __launch_bounds__(128) void bn_finalize_v_kernel(const float* __restrict__ part,
                                                            const float* __restrict__ g,
                                                            const float* __restrict__ bta,
                                                            float* __restrict__ scale,
                                                            float* __restrict__ shift) {
    int ch = threadIdx.x;
    if (ch >= CVV) return;
    int cb = ch >> 5;
    int cg = (ch & 31) >> 2;
    int i = ch & 3;
    float s1 = 0.0f, s2 = 0.0f;
    for (int n = 0; n < NN; ++n) {
        for (int mb = 0; mb < 32; ++mb) {
            int b = n * 128 + cb * 32 + mb;
            size_t idx = (((size_t)b * 8 + cg) * 4 + i) * 2;
            s1 += part[idx];
            s2 += part[idx + 1];
        }
    }
    float mean = s1 * (1.0f / (NN * LL));
    float var = s2 * (1.0f / (NN * LL)) - mean * mean;
    float inv = rsqrtf(var + 1e-5f);
    float sc = g[ch] * inv;
    scale[ch] = sc;
    shift[ch] = bta[ch] - mean * sc;
}

// ---------------- apply BN + relu -> swizzled bf16 vt (32-m tiles), 8 m/thread ----------------
__global__ __launch_bounds__(256) void bn_apply2_kernel(const ushort_t* __restrict__ val,
                                                        const float* __restrict__ scale,
                                                        const float* __restrict__ shift,
                                                        char* __restrict__ vt_c) {
    int t = blockIdx.x * 256 + threadIdx.x;   // over NN*CVV*512
    int mq = t & 511;
    int ch = (t >> 9) & 127;
    int n = t >> 16;
    int m0 = mq * 8;
    short8v vs = *(const short8v*)(val + ((size_t)(n * CVV + ch)) * LL + m0);
    float sc = scale[ch], sh = shift[ch];
    union { short8v v; ushort_t s[8]; } pk;
    #pragma unroll
    for (int i = 0; i < 8; ++i)
        pk.s[i] = f2bf(fmaxf(fmaf(bf2f((ushort_t)vs[i]), sc, sh), 0.0f));
    int tile = m0 >> 5, mloc = m0 & 31;
    size_t byte = (size_t)n * 1048576 + (size_t)tile * 8192
                + (size_t)(((ch << 6) | (mloc << 1)) ^ ((ch & 7) << 4));
    *(short8v*)(vt_c + byte) = pk.v;
}

// ---------------- swapped-QK flash attention + fused projection, KVBLK=32, 4-way m-split ----------------
__global__ __launch_bounds__(256, 4) void attn_swz_kernel(const ushort_t* __restrict__ qt,
                                                          const char* __restrict__ kt_c,
                                                          const char* __restrict__ vt_c,
                                                          const int* __restrict__ kmaxb,
                                                          const float* __restrict__ Wp,
                                                          float* __restrict__ ypart,
                                                          float* __restrict__ Lp) {
    int orig = blockIdx.x;                       // 1024
    int xcd = orig & 7;
    int idx = orig >> 3;                         // 0..127
    int qb = idx >> 1;                           // 0..63
    int combo = xcd * 2 + (idx & 1);             // 0..15 XCD-pinned (n,sM)
    int n = combo >> 2;
    int sM = combo & 3;
    int T0 = sM * 32;                            // first 32-m tile (of 128)

    int tid = threadIdx.x;
    int w = tid >> 6, lane = tid & 63, c = lane & 15, g = lane >> 4;
    int l0w = qb * 64 + w * 16;

    __shared__ __align__(16) ushort_t K_t[2][1024];   // 2 x 2KB
    __shared__ __align__(16) ushort_t V_t[2][4096];   // 2 x 8KB
    __shared__ __align__(16) uint4 exch[4][64];       // 4KB, intra-wave P exchange
    __shared__ float Wpl[COO][CVV];                   // 5KB

    for (int i = tid; i < COO * CVV; i += 256) Wpl[i >> 7][i & 127] = Wp[i];

    const char* ktb = kt_c + (size_t)n * 262144;
    const char* vtb = vt_c + (size_t)n * 1048576;

    // Q as B-operand fragment: row = c (q), k = g*8+i
    short8v qf = *(const short8v*)(qt + (((size_t)n * LL + l0w + c) << 5) + g * 8);
    int vxor = (c & 7) << 4;

    // analytic row-max bound; after the two xors every lane holds the bound for q-row c
    float Mq = 0.0f;
    {
        const int* km = kmaxb + n * 32 + g * 8;
        #pragma unroll
        for (int i = 0; i < 8; ++i) {
            float kv = __int_as_float(km[i]);
            float aq = __uint_as_float(((unsigned int)((ushort_t)qf[i]) & 0x7fffu) << 16);
            Mq = fmaf(aq, kv, Mq);
        }
        Mq += __shfl_xor(Mq, 16);
        Mq += __shfl_xor(Mq, 32);
    }

    f32x4 O[8];
    #pragma unroll
    for (int i = 0; i < 8; ++i) O[i] = (f32x4){0.f, 0.f, 0.f, 0.f};
    float Lacc = 0.0f;

    // K fragment byte offsets (A-operand: rows = m) — XOR applied to the FULL address
    int kby0, kby1;
    {
        int kr0 = c, kr1 = 16 + c;
        kby0 = ((kr0 << 6) | (g << 4)) ^ (((kr0 >> 1) & 7) << 4);
        kby1 = ((kr1 << 6) | (g << 4)) ^ (((kr1 >> 1) & 7) << 4);
    }
    int srcA = ((g & 1) << 5) + c;   // intra-wave source lane for P elems 0..3
    int toff = (g >> 1) * 8;

    // prologue staging
    {
        int T = T0;
        const char* ks = ktb + (size_t)(T >> 1) * 4096 + (T & 1) * 2048 + w * 1024 + lane * 16;
        if (w < 2) gload16(ks, (char*)K_t[0] + w * 1024);
        const char* vs = vtb + (size_t)T * 8192 + w * 2048 + lane * 16;
        gload16(vs, (char*)V_t[0] + w * 2048);
        gload16(vs + 1024, (char*)V_t[0] + w * 2048 + 1024);
    }
    __syncthreads();
    int buf = 0;
    for (int mt = 0; mt < 32; ++mt) {
        if (mt + 1 < 32) {
            int T = T0 + mt + 1;
            const char* ks = ktb + (size_t)(T >> 1) * 4096 + (T & 1) * 2048 + w * 1024 + lane * 16;
            if (w < 2) gload16(ks, (char*)K_t[buf ^ 1] + w * 1024);
            const char* vs = vtb + (size_t)T * 8192 + w * 2048 + lane * 16;
            gload16(vs, (char*)V_t[buf ^ 1] + w * 2048);
            gload16(vs + 1024, (char*)V_t[buf ^ 1] + w * 2048 + 1024);
        }
        // swapped QK: S = mfma(K, Q) -> lane holds S[m = 4g + r][q = c]
        const char* kb = (const char*)K_t[buf];
        short8v kf0 = *(const short8v*)(kb + kby0);
        short8v kf1 = *(const short8v*)(kb + kby1);
        f32x4 S0 = __builtin_amdgcn_mfma_f32_16x16x32_bf16(kf0, qf, (f32x4){0.f,0.f,0.f,0.f}, 0, 0, 0);
        f32x4 S1 = __builtin_amdgcn_mfma_f32_16x16x32_bf16(kf1, qf, (f32x4){0.f,0.f,0.f,0.f}, 0, 0, 0);
        // exp (per-lane M), accumulate L, pack to bf16 words
        float p0[4], p1[4];
        #pragma unroll
        for (int r = 0; r < 4; ++r) {
            p0[r] = __expf(S0[r] - Mq);
            p1[r] = __expf(S1[r] - Mq);
            Lacc += p0[r] + p1[r];
        }
        exch[w][lane] = (uint4){ pk2(p0[0], p0[1]), pk2(p0[2], p0[3]),
                                 pk2(p1[0], p1[1]), pk2(p1[2], p1[3]) };
        // intra-wave gather of the P A-fragment (no block barrier needed)
        const char* eb = (const char*)&exch[w][0];
        uint2 ua = *(const uint2*)(eb + srcA * 16 + toff);
        uint2 ub = *(const uint2*)(eb + (srcA + 16) * 16 + toff);
        union { unsigned int u[4]; short8v v; } pa;
        pa.u[0] = ua.x; pa.u[1] = ua.y; pa.u[2] = ub.x; pa.u[3] = ub.y;
        // PV: O[ct] += P(16q x 32m) * V(32m x 16ch)
        const char* vb = (const char*)V_t[buf];
        __builtin_amdgcn_s_setprio(1);
        #pragma unroll
        for (int ct = 0; ct < 8; ++ct) {
            int vby = (((ct * 16 + c) << 6) | (g << 4)) ^ vxor;   // FIX: XOR over full address
            short8v vf = *(const short8v*)(vb + vby);
            O[ct] = __builtin_amdgcn_mfma_f32_16x16x32_bf16(pa.v, vf, O[ct], 0, 0, 0);
        }
        __builtin_amdgcn_s_setprio(0);
        __syncthreads();
        buf ^= 1;
    }
    // L per q=c: reduce across the 4 g-groups
    Lacc += __shfl_xor(Lacc, 16);
    Lacc += __shfl_xor(Lacc, 32);
    if (g == 0)
        Lp[sM * (NN * LL) + n * LL + l0w + c] = Lacc;

    // fused projection (O layout: row q = g*4+r, col ch = ct*16+c — unchanged)
    float yp[COO][4];
    #pragma unroll
    for (int o = 0; o < COO; ++o)
        #pragma unroll
        for (int r = 0; r < 4; ++r) yp[o][r] = 0.0f;
    #pragma unroll
    for (int ct = 0; ct < 8; ++ct) {
        #pragma unroll
        for (int o = 0; o < COO; ++o) {
            float wv = Wpl[o][ct * 16 + c];
            #pragma unroll
            for (int r = 0; r < 4; ++r)
                yp[o][r] = fmaf(O[ct][r], wv, yp[o][r]);
        }
    }
    #pragma unroll
    for (int off = 1; off < 16; off <<= 1) {
        #pragma unroll
        for (int o = 0; o < COO; ++o)
            #pragma unroll
            for (int r = 0; r < 4; ++r)
                yp[o][r] += __shfl_xor(yp[o][r], off);
    }
    if (c == 0) {
        #pragma unroll
        for (int r = 0; r < 4; ++r) {
            size_t yrow = (size_t)(sM * (NN * LL) + n * LL + l0w + g * 4 + r);
            #pragma unroll
            for (int o = 0; o < COO; ++o)
                ypart[yrow * COO + o] = yp[o][r];
        }
    }
}

// ---------------- combine 4 m-splits + fused BN2 stat partials ----------------
__global__ __launch_bounds__(256) void combine4b_kernel(const float* __restrict__ ypart,
                                                        const float* __restrict__ Lp,
                                                        float* __restrict__ out_pre,
                                                        float* __restrict__ part2) {
    int idx = blockIdx.x * 256 + threadIdx.x;   // over NN*LL (64 blocks)
    int n = idx >> 12;
    int l = idx & 4095;
    int nl = n * LL + l;
    float inv = 1.0f / (Lp[nl] + Lp[16384 + nl] + Lp[2 * 16384 + nl] + Lp[3 * 16384 + nl]);
    const float* y0 = ypart + (size_t)nl * COO;
    const float* y1 = ypart + ((size_t)16384 + nl) * COO;
    const float* y2 = ypart + ((size_t)(2 * 16384) + nl) * COO;
    const float* y3 = ypart + ((size_t)(3 * 16384) + nl) * COO;
    float ov[COO];
    #pragma unroll
    for (int o = 0; o < COO; ++o) {
        ov[o] = (y0[o] + y1[o] + y2[o] + y3[o]) * inv;
        out_pre[((size_t)(n * COO + o)) * LL + l] = ov[o];
    }
    float p1[COO], p2[COO];
    #pragma unroll
    for (int o = 0; o < COO; ++o) { p1[o] = ov[o]; p2[o] = ov[o] * ov[o]; }
    #pragma unroll
    for (int off = 1; off < 64; off <<= 1) {
        #pragma unroll
        for (int o = 0; o < COO; ++o) {
            p1[o] += __shfl_xor(p1[o], off);
            p2[o] += __shfl_xor(p2[o], off);
        }
    }
    __shared__ float rs1[4][COO], rs2[4][COO];
    int w = threadIdx.x >> 6, lane = threadIdx.x & 63;
    if (lane == 0) {
        #pragma unroll
        for (int o = 0; o < COO; ++o) { rs1[w][o] = p1[o]; rs2[w][o] = p2[o]; }
    }
    __syncthreads();
    if (threadIdx.x < COO) {
        int o = threadIdx.x;
        float a = rs1[0][o] + rs1[1][o] + rs1[2][o] + rs1[3][o];
        float b = rs2[0][o] + rs2[1][o] + rs2[2][o] + rs2[3][o];
        part2[((size_t)blockIdx.x * COO + o) * 2]     = a;
        part2[((size_t)blockIdx.x * COO + o) * 2 + 1] = b;
    }
}

// ---------------- BN2 finalize ----------------
__global__ __launch_bounds__(64) void bn_finalize2_kernel(const float* __restrict__ part2,
                                                          const float* __restrict__ g,
                                                          const float* __restrict__ bta,
                                                          float* __restrict__ scale,
                                                          float* __restrict__ shift) {
    int ch = threadIdx.x;
    if (ch >= COO) return;
    float s1 = 0.0f, s2 = 0.0f;
    for (int b = 0; b < 64; ++b) {
        s1 += part2[((size_t)b * COO + ch) * 2];
        s2 += part2[((size_t)b * COO + ch) * 2 + 1];
    }
    float mean = s1 * (1.0f / (NN * LL));
    float var = s2 * (1.0f / (NN * LL)) - mean * mean;
    float inv = rsqrtf(var + 1e-5f);
    float sc = g[ch] * inv;
    scale[ch] = sc;
    shift[ch] = bta[ch] - mean * sc;
}

// ---------------- BN + relu + bilinear resize (align_corners=True) ----------------
__global__ __launch_bounds__(256) void resize_kernel(const float* __restrict__ out_pre,
                                                     const float* __restrict__ scale,
                                                     const float* __restrict__ shift,
                                                     float* __restrict__ out,
                                                     int total) {
    int idx = blockIdx.x * 256 + threadIdx.x;
    if (idx >= total) return;
    int ow = idx % HH;
    int t = idx / HH;
    int oh = t % HH;
    int t2 = t / HH;
    int o = t2 % COO;
    int n = t2 / COO;

    const float r = 63.0f / 128.0f;
    float y = oh * r;
    float x = ow * r;
    int y0 = (int)y;
    int x0 = (int)x;
    float wy = y - y0;
    float wx = x - x0;
    int y1 = min(y0 + 1, 63);
    int x1 = min(x0 + 1, 63);

    const float* base = out_pre + ((size_t)(n * COO + o)) * LL;
    float sc = scale[o], sh = shift[o];
    float v00 = fmaxf(fmaf(base[y0 * 64 + x0], sc, sh), 0.0f);
    float v01 = fmaxf(fmaf(base[y0 * 64 + x1], sc, sh), 0.0f);
    float v10 = fmaxf(fmaf(base[y1 * 64 + x0], sc, sh), 0.0f);
    float v11 = fmaxf(fmaf(base[y1 * 64 + x1], sc, sh), 0.0f);
    float top = v00 * (1.0f - wx) + v01 * wx;
    float bot = v10 * (1.0f - wx) + v11 * wx;
    out[idx] = top * (1.0f - wy) + bot * wy;
}

extern "C" void kernel_launch(void* const* d_in, const int* in_sizes, int n_in,
                              void* d_out, int out_size, void* d_ws, size_t ws_size,
                              hipStream_t stream) {
    (void)in_sizes; (void)n_in; (void)out_size; (void)ws_size;
    const float* p_fea = (const float*)d_in[0];
    const float* hu    = (const float*)d_in[1];
    const float* Wq    = (const float*)d_in[2];
    const float* Wk    = (const float*)d_in[3];
    const float* Wv    = (const float*)d_in[4];
    const float* g_v   = (const float*)d_in[5];
    const float* b_v   = (const float*)d_in[6];
    const float* Wp    = (const float*)d_in[7];
    const float* g_p   = (const float*)d_in[8];
    const float* b_p   = (const float*)d_in[9];

    float* ws = (float*)d_ws;
    ushort_t* pbb     = (ushort_t*)(ws + PB_OFF);
    float*    out_pre = ws + OP_OFF;
    ushort_t* valb    = (ushort_t*)(ws + VAL_OFF);
    ushort_t* qtb     = (ushort_t*)(ws + QT_OFF);
    char*     ktb     = (char*)(ws + KT_OFF);
    char*     vtb     = (char*)(ws + VT_OFF);
    float*    Lpart   = ws + VAL_OFF;             // alias: val dead after bn_apply2
    float*    ypart   = ws + VAL_OFF + 65536;     // [4][16384][10]
    float*    vscale  = ws + VSC_OFF;
    float*    vshift  = ws + VSH_OFF;
    float*    scale2  = ws + S2_OFF;
    float*    shift2  = ws + SH2_OFF;
    float*    part    = ws + PART_OFF;
    float*    part2   = ws + PART2_OFF;
    int*      kmaxb   = (int*)(ws + KMAX_OFF);

    pool_bf_kernel<<<NN * CIN * 16, 256, 0, stream>>>(p_fea, pbb, kmaxb);
    qkval_kernel<<<768, 256, 0, stream>>>(pbb, hu, Wq, Wk, Wv, qtb, ktb, kmaxb, valb, part);
    bn_finalize_v_kernel<<<1, 128, 0, stream>>>(part, g_v, b_v, vscale, vshift);
    bn_apply2_kernel<<<(NN * CVV * 512) / 256, 256, 0, stream>>>(valb, vscale, vshift, vtb);
    attn_swz_kernel<<<1024, 256, 0, stream>>>(qtb, ktb, vtb, kmaxb, Wp, ypart, Lpart);
    combine4b_kernel<<<(NN * LL) / 256, 256, 0, stream>>>(ypart, Lpart, out_pre, part2);
    bn_finalize2_kernel<<<1, 64, 0, stream>>>(part2, g_p, b_p, scale2, shift2);
    {
        int total = NN * COO * HH * HH;
        resize_kernel<<<(total + 255) / 256, 256, 0, stream>>>(out_pre, scale2, shift2,
                                                               (float*)d_out, total);
    }
}